// Round 7
// baseline (186.250 us; speedup 1.0000x reference)
//
#include <hip/hip_runtime.h>

// ---------------------------------------------------------------------------
// SpatialWiseSelfAttention on MI355X (gfx950), bf16 MFMA pipeline.
//   x[16,512,32,32] -> xf[8192,1024]
//   QKV = xf @ [Wq|Wk|Wv].T + b   (stacked NT GEMM, N=3072)
//   per (b,h): S = Q K^T / 8 ; P = softmax(S) ; O = P V
//   out = O @ Wo.T + bo  (fp32 out)
// GEMMs: m201-style 8-phase slot pipeline. 256x256 tile, BK=64, 8 waves
// (2Mx4N), wave C-tile 128x64. LDS 128 KB = 2 K-tile buffers. Per K-tile:
// 4 phases (C-quadrants, 16 MFMA each, reads 12/4/8/0); each phase stages
// ONE half-tile into the slot freed 1-2 phases earlier (consumed 5-7 phases
// later); boundary s_waitcnt vmcnt(4) - newest 2 half-tiles NEVER drained.
// ---------------------------------------------------------------------------

typedef unsigned short u16;
typedef __attribute__((ext_vector_type(8))) short short8;   // 8 bf16 = 4 VGPR
typedef __attribute__((ext_vector_type(4))) float f32x4;
typedef __attribute__((ext_vector_type(4))) unsigned short u16x4;

#define MFMA16(a, b, c) __builtin_amdgcn_mfma_f32_16x16x32_bf16(a, b, c, 0, 0, 0)

__device__ __forceinline__ u16 f2bf(float x) {            // RNE f32->bf16
  unsigned u = __float_as_uint(x);
  u += 0x7FFFu + ((u >> 16) & 1u);
  return (u16)(u >> 16);
}

__device__ __forceinline__ void async16(const void* g, void* l) {
  // 16B global->LDS direct; LDS dest = wave-uniform base + lane*16.
  __builtin_amdgcn_global_load_lds(
      (__attribute__((address_space(1))) unsigned int*)(g),
      (__attribute__((address_space(3))) unsigned int*)(l), 16, 0, 0);
}

// ---------------------------------------------------------------------------
// Fused fp32 -> bf16 conversion of x + Wq + Wk + Wv + Wo (contiguous dsts).
// ---------------------------------------------------------------------------
__global__ __launch_bounds__(256) void cvt_all(
    const float* __restrict__ x, const float* __restrict__ wq,
    const float* __restrict__ wk, const float* __restrict__ wv,
    const float* __restrict__ wo, u16* __restrict__ dst) {
  int g = blockIdx.x * 256 + threadIdx.x;   // group = 4 floats
  const float* s;
  int off;
  if (g < 2097152) {
    s = x; off = g;
  } else {
    int r = g - 2097152;
    int w = r >> 18;
    off = r & 262143;
    s = (w == 0) ? wq : (w == 1) ? wk : (w == 2) ? wv : wo;
  }
  f32x4 v = ((const f32x4*)s)[off];
  u16x4 o;
#pragma unroll
  for (int j = 0; j < 4; ++j) o[j] = f2bf(v[j]);
  ((u16x4*)dst)[g] = o;
}

// ---------------------------------------------------------------------------
// 8-phase slot-pipelined 256x256 NT GEMM, BK=64, K=1024 (16 tiles).
// 512 thr / 8 waves (wr=wave>>2, wn=wave&3); wave C-tile 128x64 = 8x4 frags.
// LDS: buf X in {0,1}: A[256][64] @ X*32768, B[256][64] @ X*32768+16384.
// XOR swizzle: 16B slot ^= row&7, via pre-swizzled global source (R4/R5
// proven, 0 conflicts). Half-tile h = rows [128h,128h+128) of A or B = 2
// async16 calls (8 KB each, 64 rows).
// Slot liveness per iter t (buf X=t&1): B-halves dead after ph1, A-halves
// after ph2. Stage: ph0->B1(t+1)->X^1, ph1->A1(t+1)->X^1, ph2->B0(t+2)->X,
// ph3->A0(t+2)->X. Boundary vmcnt(4): tile t+1 complete, t+2's 4 newest
// loads stay in flight.
// ---------------------------------------------------------------------------
__device__ __forceinline__ void gemm8p(const u16* __restrict__ A,
                                       const u16* __restrict__ W, int m0,
                                       int n0, u16* lds, f32x4 acc[8][4]) {
  const int t = threadIdx.x;
  const int wave = t >> 6, lane = t & 63, lr = lane & 15, lg = lane >> 4;
  const int wr = wave >> 2, wn = wave & 3;
  const int srow = t >> 3;                        // 0..63 within 64-row block
  const int scol = ((t & 7) ^ (srow & 7)) << 3;   // pre-swizzled source chunk
  const u16* gA = A + (size_t)(m0 + srow) * 1024 + scol;
  const u16* gB = W + (size_t)(n0 + srow) * 1024 + scol;
  u16* stA = lds + wave * 512;
  u16* stB = lds + 16384 + wave * 512;
  const int arow = (wr * 128 + lr) * 64;          // + mf*1024
  const int brow = 16384 + (wn * 64 + lr) * 64;   // + nf*1024
  const int xk = lr & 7;
  const int sw0 = (lg ^ xk) << 3;                 // k-half 0 slot
  const int sw1 = ((4 + lg) ^ xk) << 3;           // k-half 1 slot

  // Stage half-tile h (rows 128h..128h+127) of K-tile kt into buf kt&1.
#define SA(kt, h)                                                           \
  {                                                                         \
    async16(gA + (2 * (h)) * 65536 + (kt) * 64,                             \
            stA + ((kt) & 1) * 32768 + (2 * (h)) * 4096);                   \
    async16(gA + (2 * (h) + 1) * 65536 + (kt) * 64,                         \
            stA + ((kt) & 1) * 32768 + (2 * (h) + 1) * 4096);               \
  }
#define SB(kt, h)                                                           \
  {                                                                         \
    async16(gB + (2 * (h)) * 65536 + (kt) * 64,                             \
            stB + ((kt) & 1) * 32768 + (2 * (h)) * 4096);                   \
    async16(gB + (2 * (h) + 1) * 65536 + (kt) * 64,                         \
            stB + ((kt) & 1) * 32768 + (2 * (h) + 1) * 4096);               \
  }

  // Prologue: all of tile 0 (8 calls) + tile 1's B0,A0 (4 calls).
  SB(0, 0); SA(0, 0); SB(0, 1); SA(0, 1);
  SB(1, 0); SA(1, 0);
  asm volatile("s_waitcnt vmcnt(4)" ::: "memory");  // tile 0 complete
  __builtin_amdgcn_s_barrier();

  short8 a[8], b[8];
#pragma unroll 2
  for (int tt = 0; tt < 16; ++tt) {
    const u16* bp = lds + (tt & 1) * 32768;
    // ---- phase 0 (q0): reads mf0-3 + nf0-1; stage B1(t+1) ----
#pragma unroll
    for (int mf = 0; mf < 4; ++mf) {
      a[mf * 2 + 0] = *(const short8*)(bp + arow + mf * 1024 + sw0);
      a[mf * 2 + 1] = *(const short8*)(bp + arow + mf * 1024 + sw1);
    }
#pragma unroll
    for (int nf = 0; nf < 2; ++nf) {
      b[nf * 2 + 0] = *(const short8*)(bp + brow + nf * 1024 + sw0);
      b[nf * 2 + 1] = *(const short8*)(bp + brow + nf * 1024 + sw1);
    }
    if (tt + 1 < 16) SB(tt + 1, 1);
    __builtin_amdgcn_s_barrier();
    asm volatile("s_waitcnt lgkmcnt(0)" ::: "memory");
    __builtin_amdgcn_sched_barrier(0);
    __builtin_amdgcn_s_setprio(1);
#pragma unroll
    for (int mf = 0; mf < 4; ++mf)
#pragma unroll
      for (int nf = 0; nf < 2; ++nf) {
        acc[mf][nf] = MFMA16(a[mf * 2 + 0], b[nf * 2 + 0], acc[mf][nf]);
        acc[mf][nf] = MFMA16(a[mf * 2 + 1], b[nf * 2 + 1], acc[mf][nf]);
      }
    __builtin_amdgcn_s_setprio(0);
    __builtin_amdgcn_s_barrier();
    // ---- phase 1 (q1): reads nf2-3; stage A1(t+1) ----
#pragma unroll
    for (int nf = 2; nf < 4; ++nf) {
      b[nf * 2 + 0] = *(const short8*)(bp + brow + nf * 1024 + sw0);
      b[nf * 2 + 1] = *(const short8*)(bp + brow + nf * 1024 + sw1);
    }
    if (tt + 1 < 16) SA(tt + 1, 1);
    __builtin_amdgcn_s_barrier();
    asm volatile("s_waitcnt lgkmcnt(0)" ::: "memory");
    __builtin_amdgcn_sched_barrier(0);
    __builtin_amdgcn_s_setprio(1);
#pragma unroll
    for (int mf = 0; mf < 4; ++mf)
#pragma unroll
      for (int nf = 2; nf < 4; ++nf) {
        acc[mf][nf] = MFMA16(a[mf * 2 + 0], b[nf * 2 + 0], acc[mf][nf]);
        acc[mf][nf] = MFMA16(a[mf * 2 + 1], b[nf * 2 + 1], acc[mf][nf]);
      }
    __builtin_amdgcn_s_setprio(0);
    __builtin_amdgcn_s_barrier();
    // ---- phase 2 (q2): reads mf4-7 (B0/A0 of this buf now dead); stage B0(t+2) ----
#pragma unroll
    for (int mf = 4; mf < 8; ++mf) {
      a[(mf - 4) * 2 + 0] = *(const short8*)(bp + arow + mf * 1024 + sw0);
      a[(mf - 4) * 2 + 1] = *(const short8*)(bp + arow + mf * 1024 + sw1);
    }
    if (tt + 2 < 16) SB(tt + 2, 0);
    __builtin_amdgcn_s_barrier();
    asm volatile("s_waitcnt lgkmcnt(0)" ::: "memory");
    __builtin_amdgcn_sched_barrier(0);
    __builtin_amdgcn_s_setprio(1);
#pragma unroll
    for (int mf = 4; mf < 8; ++mf)
#pragma unroll
      for (int nf = 2; nf < 4; ++nf) {
        acc[mf][nf] = MFMA16(a[(mf - 4) * 2 + 0], b[nf * 2 + 0], acc[mf][nf]);
        acc[mf][nf] = MFMA16(a[(mf - 4) * 2 + 1], b[nf * 2 + 1], acc[mf][nf]);
      }
    __builtin_amdgcn_s_setprio(0);
    __builtin_amdgcn_s_barrier();
    // ---- phase 3 (q3): no reads; stage A0(t+2); boundary vmcnt(4) ----
    if (tt + 2 < 16) SA(tt + 2, 0);
    __builtin_amdgcn_s_setprio(1);
#pragma unroll
    for (int mf = 4; mf < 8; ++mf)
#pragma unroll
      for (int nf = 0; nf < 2; ++nf) {
        acc[mf][nf] = MFMA16(a[(mf - 4) * 2 + 0], b[nf * 2 + 0], acc[mf][nf]);
        acc[mf][nf] = MFMA16(a[(mf - 4) * 2 + 1], b[nf * 2 + 1], acc[mf][nf]);
      }
    __builtin_amdgcn_s_setprio(0);
    if (tt < 14) {
      asm volatile("s_waitcnt vmcnt(4)" ::: "memory");  // t+1 ready; t+2 in flight
    } else {
      asm volatile("s_waitcnt vmcnt(0)" ::: "memory");  // tail drain (cheap)
    }
    __builtin_amdgcn_s_barrier();
  }
#undef SA
#undef SB
}

// QKV stacked: W3 = [Wq|Wk|Wv] as [3072][1024]. Grid 384 = 32 m x 12 n,
// bijective XCD swizzle. Q,K out [b,h,c,d]; V out [b,h,d,c].
__global__ __launch_bounds__(512, 2) void gemm_qkv(
    const u16* __restrict__ xb, const u16* __restrict__ w3,
    const float* __restrict__ bq, const float* __restrict__ bk,
    const float* __restrict__ bv, u16* __restrict__ qo, u16* __restrict__ ko,
    u16* __restrict__ vo) {
  __shared__ u16 lds[65536];  // 128 KiB
  const int id = blockIdx.x;
  const int lid = (id & 7) * 48 + (id >> 3);  // 384%8==0
  const int tm = lid / 12, tn = lid % 12;
  const int m0 = tm * 256, n0g = tn * 256;
  const int z = n0g >> 10, n0 = n0g & 1023;
  const float* bias = (z == 0) ? bq : (z == 1) ? bk : bv;
  u16* outp = (z == 0) ? qo : (z == 1) ? ko : vo;
  f32x4 acc[8][4];
#pragma unroll
  for (int i = 0; i < 8; ++i)
#pragma unroll
    for (int j = 0; j < 4; ++j) acc[i][j] = (f32x4){0.f, 0.f, 0.f, 0.f};
  gemm8p(xb, w3, m0, n0g, lds, acc);

  const int t = threadIdx.x;
  const int wave = t >> 6, lane = t & 63, lr = lane & 15, lg = lane >> 4;
  const int wr = wave >> 2, wn = wave & 3;
  float bb[4];
#pragma unroll
  for (int nf = 0; nf < 4; ++nf) bb[nf] = bias[n0 + wn * 64 + nf * 16 + lr];
#pragma unroll
  for (int mf = 0; mf < 8; ++mf)
#pragma unroll
    for (int nf = 0; nf < 4; ++nf)
#pragma unroll
      for (int r = 0; r < 4; ++r) {
        int m = m0 + wr * 128 + mf * 16 + lg * 4 + r;  // D: row=(lane>>4)*4+reg
        int n = n0 + wn * 64 + nf * 16 + lr;           //    col=lane&15
        float val = acc[mf][nf][r] + bb[nf];
        int b_ = m >> 9, c = m & 511, h = n >> 6, dd = n & 63;
        int idx = (z == 2) ? ((((b_ << 4) + h) << 15) + (dd << 9) + c)
                           : ((((b_ << 4) + h) << 15) + (c << 6) + dd);
        outp[idx] = f2bf(val);
      }
}

// Output projection: fp32 out + bias. Grid 128 = 32 m x 4 n.
__global__ __launch_bounds__(512, 2) void gemm_oproj(const u16* __restrict__ ab,
                                                     const u16* __restrict__ wo,
                                                     const float* __restrict__ bo,
                                                     float* __restrict__ out) {
  __shared__ u16 lds[65536];
  const int id = blockIdx.x;
  const int lid = (id & 7) * 16 + (id >> 3);  // 128%8==0
  const int m0 = (lid >> 2) * 256, n0 = (lid & 3) * 256;
  f32x4 acc[8][4];
#pragma unroll
  for (int i = 0; i < 8; ++i)
#pragma unroll
    for (int j = 0; j < 4; ++j) acc[i][j] = (f32x4){0.f, 0.f, 0.f, 0.f};
  gemm8p(ab, wo, m0, n0, lds, acc);

  const int t = threadIdx.x;
  const int wave = t >> 6, lane = t & 63, lr = lane & 15, lg = lane >> 4;
  const int wr = wave >> 2, wn = wave & 3;
  float bb[4];
#pragma unroll
  for (int nf = 0; nf < 4; ++nf) bb[nf] = bo[n0 + wn * 64 + nf * 16 + lr];
#pragma unroll
  for (int mf = 0; mf < 8; ++mf)
#pragma unroll
    for (int nf = 0; nf < 4; ++nf)
#pragma unroll
      for (int r = 0; r < 4; ++r) {
        int m = m0 + wr * 128 + mf * 16 + lg * 4 + r;
        int n = n0 + wn * 64 + nf * 16 + lr;
        out[m * 1024 + n] = acc[mf][nf][r] + bb[nf];
      }
}

// ---------------------------------------------------------------------------
// Attention: one block per (b,h). 512 thr / 8 waves. K[512][64] and
// V^T[64][512] resident in LDS (XOR slot-swizzle). Each wave: 4 q-tiles of 16
// rows; S in regs; in-register softmax; P via 2KB/wave LDS for PV MFMA.
// Q-frags hoisted; setprio around MFMA clusters (m191).
// ---------------------------------------------------------------------------
__global__ __launch_bounds__(512, 2) void attn_kernel(
    const u16* __restrict__ qb, const u16* __restrict__ kb,
    const u16* __restrict__ vb, u16* __restrict__ ab) {
  __shared__ u16 lK[32768];   // [512 rows][64] swizzled (64 KB)
  __shared__ u16 lV[32768];   // [64 rows][512] swizzled (64 KB)
  __shared__ u16 lP[8192];    // 8 waves x [16][64] swizzled (16 KB)
  const int t = threadIdx.x;
  const int bh = blockIdx.x;
  const int b_ = bh >> 4, h_ = bh & 15;
  const u16* kg = kb + bh * 32768;
  const u16* vg = vb + bh * 32768;
#pragma unroll
  for (int i = 0; i < 8; ++i) {
    int row = i * 64 + (t >> 3), slot = t & 7;            // K: 64 rows/iter
    short8 kv = *(const short8*)(kg + row * 64 + slot * 8);
    *(short8*)(lK + row * 64 + ((slot ^ (row & 7)) << 3)) = kv;
    int vrow = i * 8 + (t >> 6), vslot = t & 63;          // V^T: 8 rows/iter
    short8 vv = *(const short8*)(vg + vrow * 512 + vslot * 8);
    *(short8*)(lV + vrow * 512 + ((vslot ^ (vrow & 7)) << 3)) = vv;
  }

  const int wv_ = t >> 6, lane = t & 63, lr = lane & 15, lg = lane >> 4;
  u16* lPw = lP + wv_ * 1024;
  const u16* qg = qb + bh * 32768;
  const float sc = 0.125f * 1.44269504088896f;  // (1/sqrt(64)) * log2(e)

  // Q-frag hoist: all 4 q-tiles' A-frags (overlaps with K/V staging above).
  short8 a0q[4], a1q[4];
#pragma unroll
  for (int qi = 0; qi < 4; ++qi) {
    const int qrow = (wv_ * 4 + qi) * 16;
    a0q[qi] = *(const short8*)(qg + (qrow + lr) * 64 + lg * 8);
    a1q[qi] = *(const short8*)(qg + (qrow + lr) * 64 + 32 + lg * 8);
  }
  __syncthreads();

#pragma unroll 1
  for (int qi = 0; qi < 4; ++qi) {
    const int qrow = (wv_ * 4 + qi) * 16;
    f32x4 s[32];
    __builtin_amdgcn_s_setprio(1);
#pragma unroll
    for (int f = 0; f < 32; ++f) {
      const u16* kr = lK + (f * 16 + lr) * 64;
      short8 k0 = *(const short8*)(kr + ((lg ^ (lr & 7)) << 3));
      short8 k1 = *(const short8*)(kr + (((4 + lg) ^ (lr & 7)) << 3));
      f32x4 z4 = (f32x4){0.f, 0.f, 0.f, 0.f};
      z4 = MFMA16(a0q[qi], k0, z4);
      z4 = MFMA16(a1q[qi], k1, z4);
      s[f] = z4;                      // D: row q = lg*4+reg, col k = f*16+lr
    }
    __builtin_amdgcn_s_setprio(0);
    float inv[4];
#pragma unroll
    for (int r = 0; r < 4; ++r) {
      float m_ = s[0][r];
#pragma unroll
      for (int f = 1; f < 32; ++f) m_ = fmaxf(m_, s[f][r]);
      m_ = fmaxf(m_, __shfl_xor(m_, 1));
      m_ = fmaxf(m_, __shfl_xor(m_, 2));
      m_ = fmaxf(m_, __shfl_xor(m_, 4));
      m_ = fmaxf(m_, __shfl_xor(m_, 8));
      float sm = 0.f;
#pragma unroll
      for (int f = 0; f < 32; ++f) {
        float e = exp2f((s[f][r] - m_) * sc);
        s[f][r] = e;
        sm += e;
      }
      sm += __shfl_xor(sm, 1);
      sm += __shfl_xor(sm, 2);
      sm += __shfl_xor(sm, 4);
      sm += __shfl_xor(sm, 8);
      inv[r] = 1.f / sm;
    }
    f32x4 o[4];
#pragma unroll
    for (int i = 0; i < 4; ++i) o[i] = (f32x4){0.f, 0.f, 0.f, 0.f};
#pragma unroll
    for (int ch = 0; ch < 8; ++ch) {
#pragma unroll
      for (int cf = 0; cf < 4; ++cf)
#pragma unroll
        for (int r = 0; r < 4; ++r) {
          int q = lg * 4 + r, kc = cf * 16 + lr;
          lPw[q * 64 + (((kc >> 3) ^ (q & 7)) << 3) + (kc & 7)] =
              f2bf(s[ch * 4 + cf][r]);
        }
      asm volatile("s_waitcnt lgkmcnt(0)" ::: "memory");
      const u16* pr = lPw + lr * 64;
      short8 pa0 = *(const short8*)(pr + ((lg ^ (lr & 7)) << 3));
      short8 pa1 = *(const short8*)(pr + (((4 + lg) ^ (lr & 7)) << 3));
      __builtin_amdgcn_s_setprio(1);
#pragma unroll
      for (int df = 0; df < 4; ++df) {
        const u16* vr = lV + (df * 16 + lr) * 512;
        short8 v0 = *(const short8*)(vr + (((ch * 8 + lg) ^ (lr & 7)) << 3));
        short8 v1 =
            *(const short8*)(vr + (((ch * 8 + 4 + lg) ^ (lr & 7)) << 3));
        o[df] = MFMA16(pa0, v0, o[df]);
        o[df] = MFMA16(pa1, v1, o[df]);
      }
      __builtin_amdgcn_s_setprio(0);
    }
#pragma unroll
    for (int df = 0; df < 4; ++df)
#pragma unroll
      for (int r = 0; r < 4; ++r) {
        int q = qrow + lg * 4 + r, dd = df * 16 + lr;
        ab[(b_ * 512 + q) * 1024 + h_ * 64 + dd] = f2bf(o[df][r] * inv[r]);
      }
  }
}

// ---------------------------------------------------------------------------
extern "C" void kernel_launch(void* const* d_in, const int* in_sizes, int n_in,
                              void* d_out, int out_size, void* d_ws,
                              size_t ws_size, hipStream_t stream) {
  (void)in_sizes; (void)n_in; (void)out_size;
  const float* x  = (const float*)d_in[0];
  const float* Wq = (const float*)d_in[1];
  const float* bq = (const float*)d_in[2];
  const float* Wk = (const float*)d_in[3];
  const float* bk = (const float*)d_in[4];
  const float* Wv = (const float*)d_in[5];
  const float* bv = (const float*)d_in[6];
  const float* Wo = (const float*)d_in[7];
  const float* bo = (const float*)d_in[8];
  float* out = (float*)d_out;

  // Workspace (bf16 elems): xb (reused as attn-out) | Wq|Wk|Wv stacked | Wo |
  // Q | K | V^T
  if (ws_size < 75497472u) return;  // 72 MB needed
  u16* xb  = (u16*)d_ws;            // 8388608 elems, dead after QKV GEMM
  u16* w3b = xb + 8388608;          // [3072][1024] stacked Wq|Wk|Wv
  u16* wob = w3b + 3145728;
  u16* qbuf = wob + 1048576;        // [b,h,c,d]
  u16* kbuf = qbuf + 8388608;       // [b,h,c,d]
  u16* vbuf = kbuf + 8388608;       // [b,h,d,c]
  u16* abuf = xb;                   // attn-out [b,c,e], aliases dead xb

  cvt_all<<<12288, 256, 0, stream>>>(x, Wq, Wk, Wv, Wo, xb);
  gemm_qkv<<<384, 512, 0, stream>>>(xb, w3b, bq, bk, bv, qbuf, kbuf, vbuf);
  attn_kernel<<<256, 512, 0, stream>>>(qbuf, kbuf, vbuf, abuf);
  gemm_oproj<<<128, 512, 0, stream>>>(abuf, wob, bo, out);
}

// Round 8
// 168.165 us; speedup vs baseline: 1.1075x; 1.1075x over previous
//
#include <hip/hip_runtime.h>

// ---------------------------------------------------------------------------
// SpatialWiseSelfAttention on MI355X (gfx950), bf16 MFMA pipeline.
//   x[16,512,32,32] -> xf[8192,1024]
//   QKV = xf @ [Wq|Wk|Wv].T + b   (stacked NT GEMM, N=3072)
//   per (b,h): S = Q K^T / 8 ; P = softmax(S) ; O = P V
//   out = O @ Wo.T + bo  (fp32 out)
// qkv: frozen 8-phase slot pipeline (256x256, BK=64, 8 waves, vmcnt(4)).
// oproj: 256x128 tile -> 256 blocks = EXACT single round on 256 CUs
//   (was 128 blocks = half machine idle). 2-phase dbuf core.
// attn: reverted to the R4-proven version.
// ---------------------------------------------------------------------------

typedef unsigned short u16;
typedef __attribute__((ext_vector_type(8))) short short8;   // 8 bf16 = 4 VGPR
typedef __attribute__((ext_vector_type(4))) float f32x4;
typedef __attribute__((ext_vector_type(4))) unsigned short u16x4;

#define MFMA16(a, b, c) __builtin_amdgcn_mfma_f32_16x16x32_bf16(a, b, c, 0, 0, 0)

__device__ __forceinline__ u16 f2bf(float x) {            // RNE f32->bf16
  unsigned u = __float_as_uint(x);
  u += 0x7FFFu + ((u >> 16) & 1u);
  return (u16)(u >> 16);
}

__device__ __forceinline__ void async16(const void* g, void* l) {
  // 16B global->LDS direct; LDS dest = wave-uniform base + lane*16.
  __builtin_amdgcn_global_load_lds(
      (__attribute__((address_space(1))) unsigned int*)(g),
      (__attribute__((address_space(3))) unsigned int*)(l), 16, 0, 0);
}

// ---------------------------------------------------------------------------
// Fused fp32 -> bf16 conversion of x + Wq + Wk + Wv + Wo (contiguous dsts).
// ---------------------------------------------------------------------------
__global__ __launch_bounds__(256) void cvt_all(
    const float* __restrict__ x, const float* __restrict__ wq,
    const float* __restrict__ wk, const float* __restrict__ wv,
    const float* __restrict__ wo, u16* __restrict__ dst) {
  int g = blockIdx.x * 256 + threadIdx.x;   // group = 4 floats
  const float* s;
  int off;
  if (g < 2097152) {
    s = x; off = g;
  } else {
    int r = g - 2097152;
    int w = r >> 18;
    off = r & 262143;
    s = (w == 0) ? wq : (w == 1) ? wk : (w == 2) ? wv : wo;
  }
  f32x4 v = ((const f32x4*)s)[off];
  u16x4 o;
#pragma unroll
  for (int j = 0; j < 4; ++j) o[j] = f2bf(v[j]);
  ((u16x4*)dst)[g] = o;
}

// ---------------------------------------------------------------------------
// FROZEN qkv core: 8-phase slot-pipelined 256x256 NT GEMM, BK=64, K=1024.
// 512 thr / 8 waves (2Mx4N); wave C-tile 128x64. LDS 128 KB = 2 buffers.
// Stage: ph0->B1(t+1), ph1->A1(t+1), ph2->B0(t+2), ph3->A0(t+2);
// boundary vmcnt(4) - newest 2 half-tiles never drained.
// ---------------------------------------------------------------------------
__device__ __forceinline__ void gemm8p(const u16* __restrict__ A,
                                       const u16* __restrict__ W, int m0,
                                       int n0, u16* lds, f32x4 acc[8][4]) {
  const int t = threadIdx.x;
  const int wave = t >> 6, lane = t & 63, lr = lane & 15, lg = lane >> 4;
  const int wr = wave >> 2, wn = wave & 3;
  const int srow = t >> 3;                        // 0..63 within 64-row block
  const int scol = ((t & 7) ^ (srow & 7)) << 3;   // pre-swizzled source chunk
  const u16* gA = A + (size_t)(m0 + srow) * 1024 + scol;
  const u16* gB = W + (size_t)(n0 + srow) * 1024 + scol;
  u16* stA = lds + wave * 512;
  u16* stB = lds + 16384 + wave * 512;
  const int arow = (wr * 128 + lr) * 64;          // + mf*1024
  const int brow = 16384 + (wn * 64 + lr) * 64;   // + nf*1024
  const int xk = lr & 7;
  const int sw0 = (lg ^ xk) << 3;                 // k-half 0 slot
  const int sw1 = ((4 + lg) ^ xk) << 3;           // k-half 1 slot

#define SA(kt, h)                                                           \
  {                                                                         \
    async16(gA + (2 * (h)) * 65536 + (kt) * 64,                             \
            stA + ((kt) & 1) * 32768 + (2 * (h)) * 4096);                   \
    async16(gA + (2 * (h) + 1) * 65536 + (kt) * 64,                         \
            stA + ((kt) & 1) * 32768 + (2 * (h) + 1) * 4096);               \
  }
#define SB(kt, h)                                                           \
  {                                                                         \
    async16(gB + (2 * (h)) * 65536 + (kt) * 64,                             \
            stB + ((kt) & 1) * 32768 + (2 * (h)) * 4096);                   \
    async16(gB + (2 * (h) + 1) * 65536 + (kt) * 64,                         \
            stB + ((kt) & 1) * 32768 + (2 * (h) + 1) * 4096);               \
  }

  // Prologue: all of tile 0 (8 calls) + tile 1's B0,A0 (4 calls).
  SB(0, 0); SA(0, 0); SB(0, 1); SA(0, 1);
  SB(1, 0); SA(1, 0);
  asm volatile("s_waitcnt vmcnt(4)" ::: "memory");  // tile 0 complete
  __builtin_amdgcn_s_barrier();

  short8 a[8], b[8];
#pragma unroll 2
  for (int tt = 0; tt < 16; ++tt) {
    const u16* bp = lds + (tt & 1) * 32768;
    // ---- phase 0 (q0): reads mf0-3 + nf0-1; stage B1(t+1) ----
#pragma unroll
    for (int mf = 0; mf < 4; ++mf) {
      a[mf * 2 + 0] = *(const short8*)(bp + arow + mf * 1024 + sw0);
      a[mf * 2 + 1] = *(const short8*)(bp + arow + mf * 1024 + sw1);
    }
#pragma unroll
    for (int nf = 0; nf < 2; ++nf) {
      b[nf * 2 + 0] = *(const short8*)(bp + brow + nf * 1024 + sw0);
      b[nf * 2 + 1] = *(const short8*)(bp + brow + nf * 1024 + sw1);
    }
    if (tt + 1 < 16) SB(tt + 1, 1);
    __builtin_amdgcn_s_barrier();
    asm volatile("s_waitcnt lgkmcnt(0)" ::: "memory");
    __builtin_amdgcn_sched_barrier(0);
    __builtin_amdgcn_s_setprio(1);
#pragma unroll
    for (int mf = 0; mf < 4; ++mf)
#pragma unroll
      for (int nf = 0; nf < 2; ++nf) {
        acc[mf][nf] = MFMA16(a[mf * 2 + 0], b[nf * 2 + 0], acc[mf][nf]);
        acc[mf][nf] = MFMA16(a[mf * 2 + 1], b[nf * 2 + 1], acc[mf][nf]);
      }
    __builtin_amdgcn_s_setprio(0);
    __builtin_amdgcn_s_barrier();
    // ---- phase 1 (q1): reads nf2-3; stage A1(t+1) ----
#pragma unroll
    for (int nf = 2; nf < 4; ++nf) {
      b[nf * 2 + 0] = *(const short8*)(bp + brow + nf * 1024 + sw0);
      b[nf * 2 + 1] = *(const short8*)(bp + brow + nf * 1024 + sw1);
    }
    if (tt + 1 < 16) SA(tt + 1, 1);
    __builtin_amdgcn_s_barrier();
    asm volatile("s_waitcnt lgkmcnt(0)" ::: "memory");
    __builtin_amdgcn_sched_barrier(0);
    __builtin_amdgcn_s_setprio(1);
#pragma unroll
    for (int mf = 0; mf < 4; ++mf)
#pragma unroll
      for (int nf = 2; nf < 4; ++nf) {
        acc[mf][nf] = MFMA16(a[mf * 2 + 0], b[nf * 2 + 0], acc[mf][nf]);
        acc[mf][nf] = MFMA16(a[mf * 2 + 1], b[nf * 2 + 1], acc[mf][nf]);
      }
    __builtin_amdgcn_s_setprio(0);
    __builtin_amdgcn_s_barrier();
    // ---- phase 2 (q2): reads mf4-7; stage B0(t+2) ----
#pragma unroll
    for (int mf = 4; mf < 8; ++mf) {
      a[(mf - 4) * 2 + 0] = *(const short8*)(bp + arow + mf * 1024 + sw0);
      a[(mf - 4) * 2 + 1] = *(const short8*)(bp + arow + mf * 1024 + sw1);
    }
    if (tt + 2 < 16) SB(tt + 2, 0);
    __builtin_amdgcn_s_barrier();
    asm volatile("s_waitcnt lgkmcnt(0)" ::: "memory");
    __builtin_amdgcn_sched_barrier(0);
    __builtin_amdgcn_s_setprio(1);
#pragma unroll
    for (int mf = 4; mf < 8; ++mf)
#pragma unroll
      for (int nf = 2; nf < 4; ++nf) {
        acc[mf][nf] = MFMA16(a[(mf - 4) * 2 + 0], b[nf * 2 + 0], acc[mf][nf]);
        acc[mf][nf] = MFMA16(a[(mf - 4) * 2 + 1], b[nf * 2 + 1], acc[mf][nf]);
      }
    __builtin_amdgcn_s_setprio(0);
    __builtin_amdgcn_s_barrier();
    // ---- phase 3 (q3): no reads; stage A0(t+2); boundary vmcnt(4) ----
    if (tt + 2 < 16) SA(tt + 2, 0);
    __builtin_amdgcn_s_setprio(1);
#pragma unroll
    for (int mf = 4; mf < 8; ++mf)
#pragma unroll
      for (int nf = 0; nf < 2; ++nf) {
        acc[mf][nf] = MFMA16(a[(mf - 4) * 2 + 0], b[nf * 2 + 0], acc[mf][nf]);
        acc[mf][nf] = MFMA16(a[(mf - 4) * 2 + 1], b[nf * 2 + 1], acc[mf][nf]);
      }
    __builtin_amdgcn_s_setprio(0);
    if (tt < 14) {
      asm volatile("s_waitcnt vmcnt(4)" ::: "memory");
    } else {
      asm volatile("s_waitcnt vmcnt(0)" ::: "memory");
    }
    __builtin_amdgcn_s_barrier();
  }
#undef SA
#undef SB
}

// ---------------------------------------------------------------------------
// oproj core: 256x128 NT GEMM, BK=64, K=1024. 8 waves (2Mx4N), wave C-tile
// 128x32 (mf=8, nf=2). LDS dbuf 96 KB: buf = A[256][64] (16384 el) +
// B[128][64] (8192 el) = 24576 el. 2 phases/K-tile, 16 MFMA each; all 6 DMA
// for t+1 issued in ph0 (into buf^1, whose readers finished last tile);
// boundary vmcnt(0) lands ~2 phases (~1240cyc) after issue > HBM latency.
// ---------------------------------------------------------------------------
__device__ __forceinline__ void gemm2x(const u16* __restrict__ A,
                                       const u16* __restrict__ W, int m0,
                                       int n0, u16* lds, f32x4 acc[8][2]) {
  const int t = threadIdx.x;
  const int wave = t >> 6, lane = t & 63, lr = lane & 15, lg = lane >> 4;
  const int wr = wave >> 2, wn = wave & 3;
  const int srow = t >> 3;
  const int scol = ((t & 7) ^ (srow & 7)) << 3;
  const u16* gA = A + (size_t)(m0 + srow) * 1024 + scol;
  const u16* gB = W + (size_t)(n0 + srow) * 1024 + scol;
  u16* stA = lds + wave * 512;            // + buf*24576 + j*4096 (j=0..3)
  u16* stB = lds + 16384 + wave * 512;    // + buf*24576 + j*4096 (j=0..1)
  const int arow = (wr * 128 + lr) * 64;          // + mf*1024
  const int brow = 16384 + (wn * 32 + lr) * 64;   // + nf*1024
  const int xk = lr & 7;
  const int sw0 = (lg ^ xk) << 3;
  const int sw1 = ((4 + lg) ^ xk) << 3;

#define SA2(kt)                                                              \
  {                                                                          \
    async16(gA + 0 * 65536 + (kt) * 64, stA + ((kt) & 1) * 24576 + 0 * 4096); \
    async16(gA + 1 * 65536 + (kt) * 64, stA + ((kt) & 1) * 24576 + 1 * 4096); \
    async16(gA + 2 * 65536 + (kt) * 64, stA + ((kt) & 1) * 24576 + 2 * 4096); \
    async16(gA + 3 * 65536 + (kt) * 64, stA + ((kt) & 1) * 24576 + 3 * 4096); \
  }
#define SB2(kt)                                                              \
  {                                                                          \
    async16(gB + 0 * 65536 + (kt) * 64, stB + ((kt) & 1) * 24576 + 0 * 4096); \
    async16(gB + 1 * 65536 + (kt) * 64, stB + ((kt) & 1) * 24576 + 1 * 4096); \
  }

  SA2(0); SB2(0);
  asm volatile("s_waitcnt vmcnt(0)" ::: "memory");
  __builtin_amdgcn_s_barrier();

  short8 a[8], b[4];
#pragma unroll 2
  for (int tt = 0; tt < 16; ++tt) {
    const u16* bp = lds + (tt & 1) * 24576;
    // ---- phase 0: read A mf0-3 + B nf0-1; stage ALL of tile t+1 ----
#pragma unroll
    for (int mf = 0; mf < 4; ++mf) {
      a[mf * 2 + 0] = *(const short8*)(bp + arow + mf * 1024 + sw0);
      a[mf * 2 + 1] = *(const short8*)(bp + arow + mf * 1024 + sw1);
    }
#pragma unroll
    for (int nf = 0; nf < 2; ++nf) {
      b[nf * 2 + 0] = *(const short8*)(bp + brow + nf * 1024 + sw0);
      b[nf * 2 + 1] = *(const short8*)(bp + brow + nf * 1024 + sw1);
    }
    if (tt + 1 < 16) { SA2(tt + 1); SB2(tt + 1); }
    __builtin_amdgcn_s_barrier();
    asm volatile("s_waitcnt lgkmcnt(0)" ::: "memory");
    __builtin_amdgcn_sched_barrier(0);
    __builtin_amdgcn_s_setprio(1);
#pragma unroll
    for (int mf = 0; mf < 4; ++mf)
#pragma unroll
      for (int nf = 0; nf < 2; ++nf) {
        acc[mf][nf] = MFMA16(a[mf * 2 + 0], b[nf * 2 + 0], acc[mf][nf]);
        acc[mf][nf] = MFMA16(a[mf * 2 + 1], b[nf * 2 + 1], acc[mf][nf]);
      }
    __builtin_amdgcn_s_setprio(0);
    __builtin_amdgcn_s_barrier();
    // ---- phase 1: read A mf4-7; MFMA mf4-7; boundary vmcnt(0) ----
#pragma unroll
    for (int mf = 4; mf < 8; ++mf) {
      a[(mf - 4) * 2 + 0] = *(const short8*)(bp + arow + mf * 1024 + sw0);
      a[(mf - 4) * 2 + 1] = *(const short8*)(bp + arow + mf * 1024 + sw1);
    }
    __builtin_amdgcn_s_barrier();
    asm volatile("s_waitcnt lgkmcnt(0)" ::: "memory");
    __builtin_amdgcn_sched_barrier(0);
    __builtin_amdgcn_s_setprio(1);
#pragma unroll
    for (int mf = 4; mf < 8; ++mf)
#pragma unroll
      for (int nf = 0; nf < 2; ++nf) {
        acc[mf][nf] = MFMA16(a[(mf - 4) * 2 + 0], b[nf * 2 + 0], acc[mf][nf]);
        acc[mf][nf] = MFMA16(a[(mf - 4) * 2 + 1], b[nf * 2 + 1], acc[mf][nf]);
      }
    __builtin_amdgcn_s_setprio(0);
    asm volatile("s_waitcnt vmcnt(0)" ::: "memory");
    __builtin_amdgcn_s_barrier();
  }
#undef SA2
#undef SB2
}

// QKV stacked: W3 = [Wq|Wk|Wv] as [3072][1024]. Grid 384 = 32 m x 12 n,
// bijective XCD swizzle. Q,K out [b,h,c,d]; V out [b,h,d,c].
__global__ __launch_bounds__(512, 2) void gemm_qkv(
    const u16* __restrict__ xb, const u16* __restrict__ w3,
    const float* __restrict__ bq, const float* __restrict__ bk,
    const float* __restrict__ bv, u16* __restrict__ qo, u16* __restrict__ ko,
    u16* __restrict__ vo) {
  __shared__ u16 lds[65536];  // 128 KiB
  const int id = blockIdx.x;
  const int lid = (id & 7) * 48 + (id >> 3);  // 384%8==0
  const int tm = lid / 12, tn = lid % 12;
  const int m0 = tm * 256, n0g = tn * 256;
  const int z = n0g >> 10, n0 = n0g & 1023;
  const float* bias = (z == 0) ? bq : (z == 1) ? bk : bv;
  u16* outp = (z == 0) ? qo : (z == 1) ? ko : vo;
  f32x4 acc[8][4];
#pragma unroll
  for (int i = 0; i < 8; ++i)
#pragma unroll
    for (int j = 0; j < 4; ++j) acc[i][j] = (f32x4){0.f, 0.f, 0.f, 0.f};
  gemm8p(xb, w3, m0, n0g, lds, acc);

  const int t = threadIdx.x;
  const int wave = t >> 6, lane = t & 63, lr = lane & 15, lg = lane >> 4;
  const int wr = wave >> 2, wn = wave & 3;
  float bb[4];
#pragma unroll
  for (int nf = 0; nf < 4; ++nf) bb[nf] = bias[n0 + wn * 64 + nf * 16 + lr];
#pragma unroll
  for (int mf = 0; mf < 8; ++mf)
#pragma unroll
    for (int nf = 0; nf < 4; ++nf)
#pragma unroll
      for (int r = 0; r < 4; ++r) {
        int m = m0 + wr * 128 + mf * 16 + lg * 4 + r;  // D: row=(lane>>4)*4+reg
        int n = n0 + wn * 64 + nf * 16 + lr;           //    col=lane&15
        float val = acc[mf][nf][r] + bb[nf];
        int b_ = m >> 9, c = m & 511, h = n >> 6, dd = n & 63;
        int idx = (z == 2) ? ((((b_ << 4) + h) << 15) + (dd << 9) + c)
                           : ((((b_ << 4) + h) << 15) + (c << 6) + dd);
        outp[idx] = f2bf(val);
      }
}

// Output projection: fp32 out + bias. Grid 256 = 32 m x 8 n (EXACT fill).
__global__ __launch_bounds__(512, 1) void gemm_oproj(const u16* __restrict__ ab,
                                                     const u16* __restrict__ wo,
                                                     const float* __restrict__ bo,
                                                     float* __restrict__ out) {
  __shared__ u16 lds[49152];  // 96 KiB
  const int id = blockIdx.x;
  const int lid = (id & 7) * 32 + (id >> 3);  // 256%8==0
  const int m0 = (lid >> 3) * 256, n0 = (lid & 7) * 128;
  f32x4 acc[8][2];
#pragma unroll
  for (int i = 0; i < 8; ++i)
#pragma unroll
    for (int j = 0; j < 2; ++j) acc[i][j] = (f32x4){0.f, 0.f, 0.f, 0.f};
  gemm2x(ab, wo, m0, n0, lds, acc);

  const int t = threadIdx.x;
  const int wave = t >> 6, lane = t & 63, lr = lane & 15, lg = lane >> 4;
  const int wr = wave >> 2, wn = wave & 3;
  float bb[2];
#pragma unroll
  for (int nf = 0; nf < 2; ++nf) bb[nf] = bo[n0 + wn * 32 + nf * 16 + lr];
#pragma unroll
  for (int mf = 0; mf < 8; ++mf)
#pragma unroll
    for (int nf = 0; nf < 2; ++nf)
#pragma unroll
      for (int r = 0; r < 4; ++r) {
        int m = m0 + wr * 128 + mf * 16 + lg * 4 + r;
        int n = n0 + wn * 32 + nf * 16 + lr;
        out[m * 1024 + n] = acc[mf][nf][r] + bb[nf];
      }
}

// ---------------------------------------------------------------------------
// Attention (R4-proven version): one block per (b,h). 512 thr / 8 waves.
// K[512][64] and V^T[64][512] in LDS (XOR slot-swizzle). Each wave: 4 q-tiles
// of 16 rows; S in regs; in-register softmax; P via 2KB/wave LDS for PV MFMA.
// ---------------------------------------------------------------------------
__global__ __launch_bounds__(512, 2) void attn_kernel(
    const u16* __restrict__ qb, const u16* __restrict__ kb,
    const u16* __restrict__ vb, u16* __restrict__ ab) {
  __shared__ u16 lK[32768];   // [512 rows][64] swizzled (64 KB)
  __shared__ u16 lV[32768];   // [64 rows][512] swizzled (64 KB)
  __shared__ u16 lP[8192];    // 8 waves x [16][64] swizzled (16 KB)
  const int t = threadIdx.x;
  const int bh = blockIdx.x;
  const int b_ = bh >> 4, h_ = bh & 15;
  const u16* kg = kb + bh * 32768;
  const u16* vg = vb + bh * 32768;
#pragma unroll
  for (int i = 0; i < 8; ++i) {
    int row = i * 64 + (t >> 3), slot = t & 7;            // K: 64 rows/iter
    short8 kv = *(const short8*)(kg + row * 64 + slot * 8);
    *(short8*)(lK + row * 64 + ((slot ^ (row & 7)) << 3)) = kv;
    int vrow = i * 8 + (t >> 6), vslot = t & 63;          // V^T: 8 rows/iter
    short8 vv = *(const short8*)(vg + vrow * 512 + vslot * 8);
    *(short8*)(lV + vrow * 512 + ((vslot ^ (vrow & 7)) << 3)) = vv;
  }
  __syncthreads();

  const int wv_ = t >> 6, lane = t & 63, lr = lane & 15, lg = lane >> 4;
  u16* lPw = lP + wv_ * 1024;
  const u16* qg = qb + bh * 32768;
  const float sc = 0.125f * 1.44269504088896f;  // (1/sqrt(64)) * log2(e)

#pragma unroll 1
  for (int qi = 0; qi < 4; ++qi) {
    const int qrow = (wv_ * 4 + qi) * 16;
    short8 a0 = *(const short8*)(qg + (qrow + lr) * 64 + lg * 8);
    short8 a1 = *(const short8*)(qg + (qrow + lr) * 64 + 32 + lg * 8);
    f32x4 s[32];
#pragma unroll
    for (int f = 0; f < 32; ++f) {
      const u16* kr = lK + (f * 16 + lr) * 64;
      short8 k0 = *(const short8*)(kr + ((lg ^ (lr & 7)) << 3));
      short8 k1 = *(const short8*)(kr + (((4 + lg) ^ (lr & 7)) << 3));
      f32x4 z4 = (f32x4){0.f, 0.f, 0.f, 0.f};
      z4 = MFMA16(a0, k0, z4);
      z4 = MFMA16(a1, k1, z4);
      s[f] = z4;                      // D: row q = lg*4+reg, col k = f*16+lr
    }
    float inv[4];
#pragma unroll
    for (int r = 0; r < 4; ++r) {
      float m_ = s[0][r];
#pragma unroll
      for (int f = 1; f < 32; ++f) m_ = fmaxf(m_, s[f][r]);
      m_ = fmaxf(m_, __shfl_xor(m_, 1));
      m_ = fmaxf(m_, __shfl_xor(m_, 2));
      m_ = fmaxf(m_, __shfl_xor(m_, 4));
      m_ = fmaxf(m_, __shfl_xor(m_, 8));
      float sm = 0.f;
#pragma unroll
      for (int f = 0; f < 32; ++f) {
        float e = exp2f((s[f][r] - m_) * sc);
        s[f][r] = e;
        sm += e;
      }
      sm += __shfl_xor(sm, 1);
      sm += __shfl_xor(sm, 2);
      sm += __shfl_xor(sm, 4);
      sm += __shfl_xor(sm, 8);
      inv[r] = 1.f / sm;
    }
    f32x4 o[4];
#pragma unroll
    for (int i = 0; i < 4; ++i) o[i] = (f32x4){0.f, 0.f, 0.f, 0.f};
#pragma unroll
    for (int ch = 0; ch < 8; ++ch) {
#pragma unroll
      for (int cf = 0; cf < 4; ++cf)
#pragma unroll
        for (int r = 0; r < 4; ++r) {
          int q = lg * 4 + r, kc = cf * 16 + lr;
          lPw[q * 64 + (((kc >> 3) ^ (q & 7)) << 3) + (kc & 7)] =
              f2bf(s[ch * 4 + cf][r]);
        }
      asm volatile("s_waitcnt lgkmcnt(0)" ::: "memory");
      const u16* pr = lPw + lr * 64;
      short8 pa0 = *(const short8*)(pr + ((lg ^ (lr & 7)) << 3));
      short8 pa1 = *(const short8*)(pr + (((4 + lg) ^ (lr & 7)) << 3));
#pragma unroll
      for (int df = 0; df < 4; ++df) {
        const u16* vr = lV + (df * 16 + lr) * 512;
        short8 v0 = *(const short8*)(vr + (((ch * 8 + lg) ^ (lr & 7)) << 3));
        short8 v1 =
            *(const short8*)(vr + (((ch * 8 + 4 + lg) ^ (lr & 7)) << 3));
        o[df] = MFMA16(pa0, v0, o[df]);
        o[df] = MFMA16(pa1, v1, o[df]);
      }
    }
#pragma unroll
    for (int df = 0; df < 4; ++df)
#pragma unroll
      for (int r = 0; r < 4; ++r) {
        int q = qrow + lg * 4 + r, dd = df * 16 + lr;
        ab[(b_ * 512 + q) * 1024 + h_ * 64 + dd] = f2bf(o[df][r] * inv[r]);
      }
  }
}

// ---------------------------------------------------------------------------
extern "C" void kernel_launch(void* const* d_in, const int* in_sizes, int n_in,
                              void* d_out, int out_size, void* d_ws,
                              size_t ws_size, hipStream_t stream) {
  (void)in_sizes; (void)n_in; (void)out_size;
  const float* x  = (const float*)d_in[0];
  const float* Wq = (const float*)d_in[1];
  const float* bq = (const float*)d_in[2];
  const float* Wk = (const float*)d_in[3];
  const float* bk = (const float*)d_in[4];
  const float* Wv = (const float*)d_in[5];
  const float* bv = (const float*)d_in[6];
  const float* Wo = (const float*)d_in[7];
  const float* bo = (const float*)d_in[8];
  float* out = (float*)d_out;

  // Workspace (bf16 elems): xb (reused as attn-out) | Wq|Wk|Wv stacked | Wo |
  // Q | K | V^T
  if (ws_size < 75497472u) return;  // 72 MB needed
  u16* xb  = (u16*)d_ws;            // 8388608 elems, dead after QKV GEMM
  u16* w3b = xb + 8388608;          // [3072][1024] stacked Wq|Wk|Wv
  u16* wob = w3b + 3145728;
  u16* qbuf = wob + 1048576;        // [b,h,c,d]
  u16* kbuf = qbuf + 8388608;       // [b,h,c,d]
  u16* vbuf = kbuf + 8388608;       // [b,h,d,c]
  u16* abuf = xb;                   // attn-out [b,c,e], aliases dead xb

  cvt_all<<<12288, 256, 0, stream>>>(x, Wq, Wk, Wv, Wo, xb);
  gemm_qkv<<<384, 512, 0, stream>>>(xb, w3b, bq, bk, bv, qbuf, kbuf, vbuf);
  attn_kernel<<<256, 512, 0, stream>>>(qbuf, kbuf, vbuf, abuf);
  gemm_oproj<<<256, 512, 0, stream>>>(abuf, wob, bo, out);
}